// Round 14
// baseline (123.691 us; speedup 1.0000x reference)
//
#include <hip/hip_runtime.h>
#include <hip/hip_bf16.h>
#include <hip/hip_fp8.h>

#define B_SZ 8192
#define D_SZ 256          // elements per row; fp8 row = 256 B
#define NTILES 2080       // (8192/128)*(8192/128+1)/2 upper-tri tiles
#define GRID_SIM 512      // 2 blocks/CU (LDS-limited), persistent
// rows pre-scaled by sqrt(log2(e)/T): exp2(acc) == exp(sim/T)
#define PRESCALE 4.539816004686735f

// s_waitcnt immediates (gfx9 encoding: vm[3:0]+[15:14], exp[6:4], lgkm[11:8])
#define WAIT_VM8 0x0F78   // vmcnt(8), lgkm/exp untouched
#define WAIT_VM0 0x0F70   // vmcnt(0), lgkm/exp untouched

typedef __attribute__((ext_vector_type(4))) float f32x4;

// ---- async global->LDS, 16B per lane (wave-uniform LDS base + lane*16) ----
__device__ __forceinline__ void async_copy16(const void* g, void* l) {
    __builtin_amdgcn_global_load_lds(
        (const __attribute__((address_space(1))) unsigned int*)g,
        (__attribute__((address_space(3))) unsigned int*)l,
        16, 0, 0);
}

// ---------------- L2-normalize rows, scale, cast to FP8 e4m3 (+ zero sums) -
__global__ __launch_bounds__(256) void norm_kernel(const float* __restrict__ emb,
                                                   unsigned char* __restrict__ nq,
                                                   float* __restrict__ sums) {
    // zero all_sum+pos_sum: 16384 floats over 256 blocks
    sums[blockIdx.x * 64 + (threadIdx.x >> 2)] = 0.0f;

    const int wave = threadIdx.x >> 6, lane = threadIdx.x & 63;
    for (int g = blockIdx.x; g < B_SZ / 4; g += 256) {
        const int row = g * 4 + wave;
        const float4 v = ((const float4*)(emb + (size_t)row * D_SZ))[lane];
        float ss = v.x * v.x + v.y * v.y + v.z * v.z + v.w * v.w;
        #pragma unroll
        for (int m = 1; m < 64; m <<= 1) ss += __shfl_xor(ss, m, 64);
        float s = PRESCALE / fmaxf(sqrtf(ss), 1e-12f);
        __hip_fp8_e4m3 q0(v.x * s), q1(v.y * s), q2(v.z * s), q3(v.w * s);
        uchar4 o;
        o.x = q0.__x; o.y = q1.__x; o.z = q2.__x; o.w = q3.__x;
        ((uchar4*)(nq + (size_t)row * D_SZ))[lane] = o;
    }
}

// ---------------- helpers ---------------------------------------------------
__device__ __forceinline__ void decode_tile(int tb, int& i0, int& j0, bool& diag) {
    int bj = (int)((sqrtf(8.0f * tb + 1.0f) - 1.0f) * 0.5f);
    while ((bj + 1) * (bj + 2) / 2 <= tb) ++bj;
    while (bj * (bj + 1) / 2 > tb) --bj;
    const int bi = tb - bj * (bj + 1) / 2;
    i0 = bi * 128; j0 = bj * 128; diag = (bi == bj);
}

// stage one 64-row x 64-B panel (wave-private), 4 DMA instrs.
// 16B-slot XOR swizzle: LDS slot s of row r holds global chunk16 s^((r>>1)&3).
__device__ __forceinline__ void issue_panel(const unsigned char* __restrict__ src,
                                            unsigned char* dst, int k0, int lane) {
    const int rowIn = lane >> 2;          // 0..15
    const int slot  = lane & 3;           // 16B slot
    #pragma unroll
    for (int q = 0; q < 4; ++q) {
        const int rl  = q * 16 + rowIn;                  // panel row 0..63
        const int c16 = slot ^ ((rl >> 1) & 3);          // source chunk16
        async_copy16(src + (size_t)rl * D_SZ + k0 + c16 * 16, dst + q * 1024);
    }
}

__device__ __forceinline__ void compute_stage(const unsigned char* sAb,
                                              const unsigned char* sBb,
                                              f32x4 acc[4][4], int lane) {
    #pragma unroll
    for (int ks = 0; ks < 2; ++ks) {
        const int C8 = ks * 4 + (lane >> 4);   // 8B chunk 0..7 in 64B window
        const int hi = C8 >> 1, lo = (C8 & 1) * 8;
        long long af[4], bf[4];
        #pragma unroll
        for (int mi = 0; mi < 4; ++mi) {
            const int rl = mi * 16 + (lane & 15);
            const int s16 = hi ^ ((rl >> 1) & 3);
            af[mi] = *(const long long*)&sAb[rl * 64 + s16 * 16 + lo];
        }
        #pragma unroll
        for (int ni = 0; ni < 4; ++ni) {
            const int rl = ni * 16 + (lane & 15);
            const int s16 = hi ^ ((rl >> 1) & 3);
            bf[ni] = *(const long long*)&sBb[rl * 64 + s16 * 16 + lo];
        }
        #pragma unroll
        for (int mi = 0; mi < 4; ++mi)
            #pragma unroll
            for (int ni = 0; ni < 4; ++ni)
                acc[mi][ni] = __builtin_amdgcn_mfma_f32_16x16x32_fp8_fp8(
                    af[mi], bf[ni], acc[mi][ni], 0, 0, 0);
    }
}

// ---------------- fused sim: wave-autonomous quadrants, ZERO barriers ------
// Each wave owns a 64x64 quadrant (wy,wx) of the 128x128 tile with private
// double-buffered LDS (16 KB/wave). Sync = per-wave s_waitcnt vmcnt(N) only.
// Next stage / next tile's stage-0 DMAs issue BEFORE the wait -> latency ages
// under compute/epilogue. Epilogue: register shuffles + global atomics.
__global__ __launch_bounds__(256) void sim_kernel(const unsigned char* __restrict__ N,
                                                  const int* __restrict__ ids,
                                                  float* __restrict__ all_sum,
                                                  float* __restrict__ pos_sum) {
    __shared__ __align__(16) unsigned char smem[65536];   // 4 waves x 2 buf x 8 KB

    const int t    = threadIdx.x;
    const int wave = t >> 6, lane = t & 63;
    const int wy   = wave >> 1, wx = wave & 1;
    const int myc  = lane & 15;
    unsigned char* lds = smem + wave * 16384;   // [buf0: A|B][buf1: A|B]

    int tb = blockIdx.x;
    int i0, j0; bool diag;
    decode_tile(tb, i0, j0, diag);
    const unsigned char* gA = N + (size_t)(i0 + wy * 64) * D_SZ;
    const unsigned char* gB = N + (size_t)(j0 + wx * 64) * D_SZ;

    // stage 0 of first tile -> buf0
    issue_panel(gA, lds, 0, lane);
    issue_panel(gB, lds + 4096, 0, lane);

    while (true) {
        const int ntb = tb + GRID_SIM;
        const bool have_next = (ntb < NTILES);
        int ni0 = i0, nj0 = j0; bool ndiag = diag;
        if (have_next) decode_tile(ntb, ni0, nj0, ndiag);
        const unsigned char* ngA = N + (size_t)(ni0 + wy * 64) * D_SZ;
        const unsigned char* ngB = N + (size_t)(nj0 + wx * 64) * D_SZ;

        f32x4 acc[4][4];
        #pragma unroll
        for (int mi = 0; mi < 4; ++mi)
            #pragma unroll
            for (int ni = 0; ni < 4; ++ni)
                acc[mi][ni] = (f32x4){0.f, 0.f, 0.f, 0.f};

        #pragma unroll
        for (int kk = 0; kk < 4; ++kk) {
            unsigned char* cur = lds + (kk & 1) * 8192;
            unsigned char* nxt = lds + ((kk + 1) & 1) * 8192;
            if (kk < 3) {
                // prefetch same tile's next stage (nxt buf consumed 2 stages ago)
                issue_panel(gA, nxt, (kk + 1) * 64, lane);
                issue_panel(gB, nxt + 4096, (kk + 1) * 64, lane);
                __builtin_amdgcn_s_waitcnt(WAIT_VM8);   // oldest 8 (stage kk) done
            } else if (have_next) {
                // prefetch next tile's stage 0; it ages under the epilogue
                issue_panel(ngA, nxt, 0, lane);
                issue_panel(ngB, nxt + 4096, 0, lane);
                __builtin_amdgcn_s_waitcnt(WAIT_VM8);
            } else {
                __builtin_amdgcn_s_waitcnt(WAIT_VM0);
            }
            compute_stage(cur, cur + 4096, acc, lane);
        }

        // ---- epilogue (registers + shuffles + global atomics) ----
        // C/D map: col=lane&15, row=(lane>>4)*4+reg (quadrant-local)
        const int R0 = i0 + wy * 64;
        const int C0 = j0 + wx * 64;
        int idc[4];
        #pragma unroll
        for (int ni = 0; ni < 4; ++ni)
            idc[ni] = ids[C0 + ni * 16 + myc];

        float cAll[4] = {0.f, 0.f, 0.f, 0.f};
        float cPos[4] = {0.f, 0.f, 0.f, 0.f};

        #pragma unroll
        for (int mi = 0; mi < 4; ++mi) {
            const int rb = mi * 16 + (lane >> 4) * 4;
            const int4 idr = *(const int4*)&ids[R0 + rb];
            float rAll[4] = {0.f, 0.f, 0.f, 0.f};
            float rPos[4] = {0.f, 0.f, 0.f, 0.f};
            #pragma unroll
            for (int ni = 0; ni < 4; ++ni) {
                #pragma unroll
                for (int rg = 0; rg < 4; ++rg) {
                    float e = __builtin_amdgcn_exp2f(acc[mi][ni][rg]);
                    if (diag && wy == wx && (rb + rg) == (ni * 16 + myc)) e = 0.0f;
                    rAll[rg] += e; cAll[ni] += e;
                    const int idrv = (rg == 0) ? idr.x : (rg == 1) ? idr.y
                                   : (rg == 2) ? idr.z : idr.w;
                    if (idrv == idc[ni]) { rPos[rg] += e; cPos[ni] += e; }
                }
            }
            #pragma unroll
            for (int rg = 0; rg < 4; ++rg) {
                #pragma unroll
                for (int mm = 1; mm < 16; mm <<= 1) {
                    rAll[rg] += __shfl_xor(rAll[rg], mm, 64);
                    rPos[rg] += __shfl_xor(rPos[rg], mm, 64);
                }
            }
            if (myc == 0) {
                #pragma unroll
                for (int rg = 0; rg < 4; ++rg) {
                    atomicAdd(&all_sum[R0 + rb + rg], rAll[rg]);
                    if (rPos[rg] != 0.0f) atomicAdd(&pos_sum[R0 + rb + rg], rPos[rg]);
                }
            }
        }

        // column sums -> rows j (off-diagonal tiles only; symmetry)
        if (!diag) {
            #pragma unroll
            for (int ni = 0; ni < 4; ++ni) {
                cAll[ni] += __shfl_xor(cAll[ni], 16, 64);
                cAll[ni] += __shfl_xor(cAll[ni], 32, 64);
                cPos[ni] += __shfl_xor(cPos[ni], 16, 64);
                cPos[ni] += __shfl_xor(cPos[ni], 32, 64);
            }
            if (lane < 16) {
                #pragma unroll
                for (int ni = 0; ni < 4; ++ni) {
                    atomicAdd(&all_sum[C0 + ni * 16 + lane], cAll[ni]);
                    if (cPos[ni] != 0.0f) atomicAdd(&pos_sum[C0 + ni * 16 + lane], cPos[ni]);
                }
            }
        }

        if (!have_next) break;
        tb = ntb; i0 = ni0; j0 = nj0; diag = ndiag; gA = ngA; gB = ngB;
    }
}

// ---------------- final scalar reduce ----------------
__global__ __launch_bounds__(256) void loss_kernel(const float* __restrict__ all_sum,
                                                   const float* __restrict__ pos_sum,
                                                   float* __restrict__ out) {
    float loss = 0.0f, cnt = 0.0f;
    for (int i = threadIdx.x; i < B_SZ; i += 256) {
        float p = pos_sum[i], a = all_sum[i];
        if (p > 0.0f) { loss += logf(a) - logf(p); cnt += 1.0f; }
    }
    #pragma unroll
    for (int m = 1; m < 64; m <<= 1) {
        loss += __shfl_xor(loss, m, 64);
        cnt  += __shfl_xor(cnt, m, 64);
    }
    __shared__ float sl[4], sc[4];
    int wave = threadIdx.x >> 6, lane = threadIdx.x & 63;
    if (lane == 0) { sl[wave] = loss; sc[wave] = cnt; }
    __syncthreads();
    if (threadIdx.x == 0) {
        float L = sl[0] + sl[1] + sl[2] + sl[3];
        float C = sc[0] + sc[1] + sc[2] + sc[3];
        out[0] = L / fmaxf(C, 1.0f);
    }
}

extern "C" void kernel_launch(void* const* d_in, const int* in_sizes, int n_in,
                              void* d_out, int out_size, void* d_ws, size_t ws_size,
                              hipStream_t stream) {
    const float* emb = (const float*)d_in[0];
    const int*   ids = (const int*)d_in[1];
    float*       out = (float*)d_out;

    float*         all_sum = (float*)d_ws;
    float*         pos_sum = all_sum + B_SZ;
    unsigned char* nq      = (unsigned char*)d_ws + 65536;   // 8192*256 fp8 = 2 MB

    norm_kernel<<<256, 256, 0, stream>>>(emb, nq, all_sum);
    sim_kernel<<<GRID_SIM, 256, 0, stream>>>(nq, ids, all_sum, pos_sum);
    loss_kernel<<<1, 256, 0, stream>>>(all_sum, pos_sum, out);
}